// Round 10
// baseline (104.473 us; speedup 1.0000x reference)
//
#include <hip/hip_runtime.h>
#include <math.h>

#define PROJ 8192
#define NB   16
#define NC   512
#define HW   196    // 14*14
#define NKC  7      // K chunks of 32 (196 zero-padded to 224)
#define LST  40     // LDS row stride in bf16 elems (80 B: b128-aligned, 2-way banks = free)

typedef __attribute__((ext_vector_type(8))) short bf16x8;   // MFMA A/B frag
typedef __attribute__((ext_vector_type(4))) short short4v;
typedef __attribute__((ext_vector_type(4))) float f32x4;    // MFMA C/D frag

__device__ __forceinline__ unsigned bf16_rne(float f) {
    unsigned u = __builtin_bit_cast(unsigned, f);
    return (u + 0x7fffu + ((u >> 16) & 1u)) >> 16;
}

// ---------------------------------------------------------------------------
// Kernel 1: split-bf16 MFMA Gram (128x128 tile) + LDS-sketch scatter ->
// global atomicAdd into per-batch sketch. Arithmetic identical to baseline.
//
// R9 lesson: 1 block/CU means __syncthreads() stalls the WHOLE CU -- the
// kernel time is the serial chain through 15 barrier phases, each riding a
// full global-load drain (structure-invariant ~41us across R0/R5/R8/R9;
// occupancy doubling moved it only -8%).
// THIS ROUND: all global loads + f32->split-bf16 converts hoisted into ONE
// prologue burst (14 float4 + convert = 56 VGPR of per-chunk shorts, all
// statically indexed via full unroll). K-loop = barrier, 4 ds_write,
// barrier, ds_read + 12 MFMA -- no vmem, no convert: inter-barrier phases
// drop from global-latency to LDS-latency.
// grid = 256 blocks x 1024 threads (16 waves, 32x32 sub-tile per wave).
//   block -> (batch,tile): b = 2*(blk&7) + (blk>>7), tile = (blk>>3)&15
// ---------------------------------------------------------------------------
__global__ __launch_bounds__(1024, 4)
void cbp_gram_mfma(const float* __restrict__ x,
                   const float* __restrict__ s1,
                   const float* __restrict__ s2,
                   const int*   __restrict__ h1,
                   const int*   __restrict__ h2,
                   float* __restrict__ gsk) {
    __shared__ float sk[PROJ];         // 32 KB private sketch
    __shared__ short Ah[128 * LST];    // 10 KB each
    __shared__ short Al[128 * LST];
    __shared__ short Bh[128 * LST];
    __shared__ short Bl[128 * LST];
    __shared__ int   lh1[128], lh2[128];

    const int tid = threadIdx.x;
    const int blk = blockIdx.x;
    const int b    = 2 * (blk & 7) + (blk >> 7);   // XCD-pinned batch
    const int tile = (blk >> 3) & 15;
    const int I = tile >> 2, J = tile & 3;
    const int c1base = I * 128;
    const int c2base = J * 128;

    const int lane = tid & 63;
    const int wave = tid >> 6;         // 0..15
    const int quad = lane >> 4;
    const int l15  = lane & 15;
    const int wr   = (wave >> 2) * 32; // wave's 32x32 sub-tile
    const int wc   = (wave & 3) * 32;

    for (int i = tid; i < PROJ; i += 1024) sk[i] = 0.f;
    if (tid < 128) { lh1[tid] = h1[c1base + tid]; lh2[tid] = h2[c2base + tid]; }

    // Staging: thread owns row sr0 (0..127), float4 slot sq (0..7).
    const int sr0 = tid >> 3;
    const int sq  = tid & 7;

    const float* xa = x + ((size_t)b * NC + c1base) * HW + sr0 * HW;
    const float* xb = x + ((size_t)b * NC + c2base) * HW + sr0 * HW;
    const float sA = s1[c1base + sr0];     // signs direct from global
    const float sB = s2[c2base + sr0];

    // ---- prologue: ALL loads + ALL converts, one parallel burst ----
    short4v cah[NKC], cal[NKC], cbh[NKC], cbl[NKC];
    {
        const float4 z4 = {0.f, 0.f, 0.f, 0.f};
        float4 pa[NKC], pb[NKC];
#pragma unroll
        for (int kc = 0; kc < NKC; ++kc) {
            const int kk = kc * 32 + 4 * sq;
            const bool ok = (kk + 3 < HW);
            pa[kc] = ok ? *(const float4*)&xa[kk] : z4;
            pb[kc] = ok ? *(const float4*)&xb[kk] : z4;
        }
#pragma unroll
        for (int kc = 0; kc < NKC; ++kc) {
            const float fa[4] = {pa[kc].x*sA, pa[kc].y*sA, pa[kc].z*sA, pa[kc].w*sA};
            const float fb[4] = {pb[kc].x*sB, pb[kc].y*sB, pb[kc].z*sB, pb[kc].w*sB};
            short4v ah, al, bh, bl;
#pragma unroll
            for (int c = 0; c < 4; ++c) {
                const unsigned ha_ = bf16_rne(fa[c]);
                ah[c] = (short)ha_;
                al[c] = (short)bf16_rne(fa[c] - __builtin_bit_cast(float, ha_ << 16));
                const unsigned hb_ = bf16_rne(fb[c]);
                bh[c] = (short)hb_;
                bl[c] = (short)bf16_rne(fb[c] - __builtin_bit_cast(float, hb_ << 16));
            }
            cah[kc] = ah; cal[kc] = al; cbh[kc] = bh; cbl[kc] = bl;
        }
    }

    f32x4 acc[2][2];
#pragma unroll
    for (int i = 0; i < 2; ++i)
#pragma unroll
        for (int j = 0; j < 2; ++j) acc[i][j] = (f32x4){0.f, 0.f, 0.f, 0.f};

    // ---- K-loop: pure LDS + MFMA (no vmem, no convert) ----
#pragma unroll
    for (int kc = 0; kc < NKC; ++kc) {
        __syncthreads();               // prev chunk's reads done; LDS free
        *(short4v*)&Ah[sr0 * LST + 4 * sq] = cah[kc];
        *(short4v*)&Al[sr0 * LST + 4 * sq] = cal[kc];
        *(short4v*)&Bh[sr0 * LST + 4 * sq] = cbh[kc];
        *(short4v*)&Bl[sr0 * LST + 4 * sq] = cbl[kc];
        __syncthreads();

        bf16x8 ahf[2], alf[2], bhf[2], blf[2];
#pragma unroll
        for (int i = 0; i < 2; ++i) {
            const int ra = wr + i * 16 + l15;
            ahf[i] = *(const bf16x8*)&Ah[ra * LST + quad * 8];
            alf[i] = *(const bf16x8*)&Al[ra * LST + quad * 8];
        }
#pragma unroll
        for (int j = 0; j < 2; ++j) {
            const int rb = wc + j * 16 + l15;
            bhf[j] = *(const bf16x8*)&Bh[rb * LST + quad * 8];
            blf[j] = *(const bf16x8*)&Bl[rb * LST + quad * 8];
        }
#pragma unroll
        for (int i = 0; i < 2; ++i)
#pragma unroll
            for (int j = 0; j < 2; ++j) {
                acc[i][j] = __builtin_amdgcn_mfma_f32_16x16x32_bf16(ahf[i], bhf[j], acc[i][j], 0, 0, 0);
                acc[i][j] = __builtin_amdgcn_mfma_f32_16x16x32_bf16(ahf[i], blf[j], acc[i][j], 0, 0, 0);
                acc[i][j] = __builtin_amdgcn_mfma_f32_16x16x32_bf16(alf[i], bhf[j], acc[i][j], 0, 0, 0);
            }
    }
    __syncthreads();

    // Scatter (signs pre-folded): C/D layout col=lane&15, row=quad*4+reg.
#pragma unroll
    for (int i = 0; i < 2; ++i) {
        const int lr0 = wr + i * 16 + quad * 4;
#pragma unroll
        for (int j = 0; j < 2; ++j) {
            const int h2v = lh2[wc + j * 16 + l15];
#pragma unroll
            for (int rg = 0; rg < 4; ++rg) {
                const int bin = (lh1[lr0 + rg] + h2v) & (PROJ - 1);
                atomicAdd(&sk[bin], acc[i][j][rg]);   // ds_add_f32
            }
        }
    }
    __syncthreads();

    // Accumulate private sketch into the batch's global sketch (coalesced
    // global_atomic_add_f32; <=16 writers/bin; gsk zeroed by hipMemsetAsync).
    float* gs = gsk + (size_t)b * PROJ;
    for (int i = tid; i < PROJ; i += 1024) atomicAdd(&gs[i], sk[i]);
}

__device__ __forceinline__ float ssqrt(float s) {
    const float m = sqrtf(fabsf(s) + 1e-8f);
    return (s > 0.f) ? m : (s < 0.f ? -m : 0.f);   // sign(0)=0
}

// ---------------------------------------------------------------------------
// Kernel 2: per-batch finalize. grid = 16 x 512. Read the batch sketch
// (512 KB total, L2-hot from the atomics), signed sqrt, ssq shuffle-reduce,
// normalize, single y write.
// ---------------------------------------------------------------------------
__global__ __launch_bounds__(512)
void cbp_finalize(const float* __restrict__ gsk, float* __restrict__ y) {
    __shared__ float red[8];
    const int b   = blockIdx.x;
    const int tid = threadIdx.x;
    const float4* gp = (const float4*)(gsk + (size_t)b * PROJ);

    float4 ov[4];
    float ssq = 0.f;
#pragma unroll
    for (int g = 0; g < 4; ++g) {
        const float4 s = gp[tid + 512 * g];
        float4 o;
        o.x = ssqrt(s.x); o.y = ssqrt(s.y); o.z = ssqrt(s.z); o.w = ssqrt(s.w);
        ov[g] = o;
        ssq += o.x * o.x + o.y * o.y + o.z * o.z + o.w * o.w;
    }

    float v = ssq;
#pragma unroll
    for (int off = 32; off >= 1; off >>= 1) v += __shfl_xor(v, off, 64);
    if ((tid & 63) == 0) red[tid >> 6] = v;
    __syncthreads();
    float tot = 0.f;
#pragma unroll
    for (int w = 0; w < 8; ++w) tot += red[w];
    const float inv = 1.0f / fmaxf(sqrtf(tot), 1e-12f);

    float4* yp = (float4*)(y + (size_t)b * PROJ);
#pragma unroll
    for (int g = 0; g < 4; ++g) {
        float4 o = ov[g];
        o.x *= inv; o.y *= inv; o.z *= inv; o.w *= inv;
        yp[tid + 512 * g] = o;
    }
}

// ---------------------------------------------------------------------------
extern "C" void kernel_launch(void* const* d_in, const int* in_sizes, int n_in,
                              void* d_out, int out_size, void* d_ws, size_t ws_size,
                              hipStream_t stream) {
    const float* x  = (const float*)d_in[0];
    const float* s1 = (const float*)d_in[1];
    const float* s2 = (const float*)d_in[2];
    const int*   h1 = (const int*)d_in[3];
    const int*   h2 = (const int*)d_in[4];
    float* y   = (float*)d_out;                    // [16, 8192]
    float* gsk = (float*)d_ws;                     // 16 batch sketches (512 KB)

    hipMemsetAsync(gsk, 0, (size_t)NB * PROJ * sizeof(float), stream);
    hipLaunchKernelGGL(cbp_gram_mfma, dim3(256), dim3(1024), 0, stream,
                       x, s1, s2, h1, h2, gsk);
    hipLaunchKernelGGL(cbp_finalize, dim3(16), dim3(512), 0, stream, gsk, y);
}